// Round 1
// baseline (79.971 us; speedup 1.0000x reference)
//
#include <hip/hip_runtime.h>

// Input order (setup_inputs): 0:x0 1:x1_src 2:w0 3:b0 4:w1 5:b1
//                             6:wm 7:bm 8:wo 9:bo 10:wl 11:bl
// All float32. Output: [8,3,32,32] float32 (24576 elements).
//
// Algebraic collapse: softmax over a size-1 axis == 1.0, so the attention
// pipeline reduces to:
//   m[c] = bm[c] + sum_k wm[c,k]
//   v[o] = bo[o] + sum_c wo[o,c] * m[c]          (o in 0..2)
//   out[b,o,p] = bl[o] + sum_c wl[o,c] * (v[c] + x1_src[b,c,p])

#define C 256
#define HW 1024
#define B 8

// Kernel A: per-block partial of v_big[o] = sum_c wo[o,c]*(bm[c] + rowsum(wm[c,:]))
// 32 blocks, block j handles rows c in [8j, 8j+8). Writes part[j*4 + o].
__global__ __launch_bounds__(256) void
vpart_kernel(const float* __restrict__ wm, const float* __restrict__ bm,
             const float* __restrict__ wo, float* __restrict__ part) {
    __shared__ float s[256];
    __shared__ float s2[3][8];
    const int j = blockIdx.x;
    const int t = threadIdx.x;

    // 8 rows * 256 cols = 2048 floats = 512 float4; thread t loads 2 float4.
    const float4* wmv = (const float4*)(wm + (size_t)j * 8 * C);
    float4 a = wmv[t * 2];
    float4 b = wmv[t * 2 + 1];
    s[t] = (a.x + a.y + a.z + a.w) + (b.x + b.y + b.z + b.w);
    __syncthreads();

    if (t < 8) {
        float rs = 0.f;
#pragma unroll
        for (int i = 0; i < 32; ++i) rs += s[t * 32 + i];
        const int c = j * 8 + t;
        rs += bm[c];
        s2[0][t] = wo[c] * rs;
        s2[1][t] = wo[C + c] * rs;
        s2[2][t] = wo[2 * C + c] * rs;
    }
    __syncthreads();

    if (t < 3) {
        float v = 0.f;
#pragma unroll
        for (int i = 0; i < 8; ++i) v += s2[t][i];
        part[j * 4 + t] = v;
    }
}

// Kernel B: final elementwise. 32 blocks * 256 threads = 8192 = B*HW pixels.
__global__ __launch_bounds__(256) void
out_kernel(const float* __restrict__ x1s, const float* __restrict__ part,
           const float* __restrict__ bo, const float* __restrict__ wl,
           const float* __restrict__ bl, float* __restrict__ out) {
    // Reduce the 32 per-block partials (uniform across the wave; cheap L2 hits).
    float v0 = bo[0], v1 = bo[1], v2 = bo[2];
#pragma unroll
    for (int jj = 0; jj < 32; ++jj) {
        v0 += part[jj * 4 + 0];
        v1 += part[jj * 4 + 1];
        v2 += part[jj * 4 + 2];
    }

    const float l00 = wl[0], l01 = wl[1], l02 = wl[2];
    const float l10 = wl[3], l11 = wl[4], l12 = wl[5];
    const float l20 = wl[6], l21 = wl[7], l22 = wl[8];
    const float c0 = bl[0], c1 = bl[1], c2 = bl[2];

    const int idx = blockIdx.x * 256 + threadIdx.x;   // 0..8191
    const int b = idx >> 10;
    const int p = idx & 1023;

    const float* xb = x1s + (size_t)b * 3 * HW;
    float t0 = v0 + xb[p];
    float t1 = v1 + xb[HW + p];
    float t2 = v2 + xb[2 * HW + p];

    float* ob = out + (size_t)b * 3 * HW;
    ob[p]          = c0 + l00 * t0 + l01 * t1 + l02 * t2;
    ob[HW + p]     = c1 + l10 * t0 + l11 * t1 + l12 * t2;
    ob[2 * HW + p] = c2 + l20 * t0 + l21 * t1 + l22 * t2;
}

extern "C" void kernel_launch(void* const* d_in, const int* in_sizes, int n_in,
                              void* d_out, int out_size, void* d_ws, size_t ws_size,
                              hipStream_t stream) {
    const float* x1_src = (const float*)d_in[1];
    const float* wm = (const float*)d_in[6];
    const float* bm = (const float*)d_in[7];
    const float* wo = (const float*)d_in[8];
    const float* bo = (const float*)d_in[9];
    const float* wl = (const float*)d_in[10];
    const float* bl = (const float*)d_in[11];

    float* part = (float*)d_ws;              // 32 * 4 floats = 512 B
    float* out = (float*)d_out;

    vpart_kernel<<<32, 256, 0, stream>>>(wm, bm, wo, part);
    out_kernel<<<32, 256, 0, stream>>>(x1_src, part, bo, wl, bl, out);
}